// Round 4
// baseline (317.438 us; speedup 1.0000x reference)
//
#include <hip/hip_runtime.h>

// Aggregator: B=8192, H=10, N=25, F=128, D=256 (half=128). Rows = B*H = 81920.
// out[row][0:128]   = relu(x_self[row]          @ w_self  + bias[0:128])
// out[row][128:256] = relu(mean_n(x_neigh[row]) @ w_neigh + bias[128:256])
//
// R4: software-pipelined across tiles (double-buffered LDS). Each block owns a
// contiguous run of 8-row tiles; loads for tile t+1 are ISSUED before compute
// of tile t and consumed (vmcnt wait + reduce + ds_write) after it, so HBM
// streaming runs under compute instead of serializing with it.
// R0-R3 all ~240us = 186us (HBM ideal) + ~50us (VALU) -- i.e. zero overlap.

#define RPB 8

__global__ __launch_bounds__(256, 2) void agg_pipe_kernel(
    const float* __restrict__ x_self,   // [rows][128]
    const float* __restrict__ x_neigh,  // [rows][25][128]
    const float* __restrict__ w_neigh,  // [128][128]
    const float* __restrict__ w_self,   // [128][128]
    const float* __restrict__ bias,     // [256]
    float* __restrict__ out,            // [rows][256]
    int rows, int tiles_per_block)
{
    __shared__ float xs[2][RPB][128];
    __shared__ float ag[2][RPB][128];

    const int tid = threadIdx.x;
    const int sr  = tid >> 5;       // staging row 0..7
    const int sv  = tid & 31;       // staging float4 column

    const int ntiles = rows / RPB;
    const int tile0  = blockIdx.x * tiles_per_block;
    if (tile0 >= ntiles) return;
    const int tend = min(tile0 + tiles_per_block, ntiles);

    const float4* xs4 = (const float4*)x_self;
    const float4* xn4 = (const float4*)x_neigh;

    // compute-phase mapping: thread = 4-row group x 2-col group
    const int rg4 = (tid >> 7) * 4;     // 0 or 4
    const int cg  = tid & 127;
    const int c0  = cg * 2;             // output column pair
    const int sel = c0 >> 7;            // 0 = self half, 1 = neigh half (wave-uniform)
    const int wc  = c0 & 127;
    const float* __restrict__ w = sel ? w_neigh : w_self;
    const float2 b2 = *(const float2*)&bias[c0];

    float4 st[25];   // staged neighbor rows (in flight across compute)
    float4 ss;       // staged x_self

    auto stage = [&](int t) {
        const size_t row = (size_t)t * RPB + sr;
        ss = xs4[row * 32 + sv];
        const size_t base = row * 800 + sv;   // float4 units; row stride 25*32
        #pragma unroll
        for (int n = 0; n < 25; ++n) st[n] = xn4[base + (size_t)n * 32];
    };

    auto reduce_write = [&](int buf) {
        float4 a = st[0];
        #pragma unroll
        for (int n = 1; n < 25; ++n) {
            a.x += st[n].x; a.y += st[n].y; a.z += st[n].z; a.w += st[n].w;
        }
        const float inv = 1.0f / 25.0f;
        a.x *= inv; a.y *= inv; a.z *= inv; a.w *= inv;
        *(float4*)&ag[buf][sr][sv * 4] = a;
        *(float4*)&xs[buf][sr][sv * 4] = ss;
    };

    auto compute_store = [&](int t, int buf) {
        const float (*vec)[128] = sel ? ag[buf] : xs[buf];
        float2 acc[4];
        #pragma unroll
        for (int rr = 0; rr < 4; ++rr) acc[rr] = make_float2(0.f, 0.f);

        for (int f4 = 0; f4 < 32; ++f4) {
            const float2 w0 = *(const float2*)&w[(f4 * 4 + 0) * 128 + wc];
            const float2 w1 = *(const float2*)&w[(f4 * 4 + 1) * 128 + wc];
            const float2 w2 = *(const float2*)&w[(f4 * 4 + 2) * 128 + wc];
            const float2 w3 = *(const float2*)&w[(f4 * 4 + 3) * 128 + wc];
            #pragma unroll
            for (int rr = 0; rr < 4; ++rr) {
                const float4 xv = *(const float4*)&vec[rg4 + rr][f4 * 4]; // broadcast
                acc[rr].x = fmaf(xv.x, w0.x, acc[rr].x);
                acc[rr].y = fmaf(xv.x, w0.y, acc[rr].y);
                acc[rr].x = fmaf(xv.y, w1.x, acc[rr].x);
                acc[rr].y = fmaf(xv.y, w1.y, acc[rr].y);
                acc[rr].x = fmaf(xv.z, w2.x, acc[rr].x);
                acc[rr].y = fmaf(xv.z, w2.y, acc[rr].y);
                acc[rr].x = fmaf(xv.w, w3.x, acc[rr].x);
                acc[rr].y = fmaf(xv.w, w3.y, acc[rr].y);
            }
        }
        #pragma unroll
        for (int rr = 0; rr < 4; ++rr) {
            float2 o;
            o.x = fmaxf(acc[rr].x + b2.x, 0.f);
            o.y = fmaxf(acc[rr].y + b2.y, 0.f);
            *(float2*)&out[((size_t)t * RPB + rg4 + rr) * 256 + c0] = o;
        }
    };

    // prologue: stage + commit tile0 into buffer 0
    stage(tile0);
    reduce_write(0);
    __syncthreads();

    int cur = 0;
    for (int t = tile0; t < tend; ++t) {
        const bool has_next = (t + 1 < tend);
        if (has_next) stage(t + 1);       // issue loads only (stay in flight)
        compute_store(t, cur);            // LDS + L2-hot weights, no vmcnt dep
        if (has_next) {
            reduce_write(cur ^ 1);        // vmcnt wait lands here, after compute
            __syncthreads();
        }
        cur ^= 1;
    }
}

extern "C" void kernel_launch(void* const* d_in, const int* in_sizes, int n_in,
                              void* d_out, int out_size, void* d_ws, size_t ws_size,
                              hipStream_t stream) {
    const float* x_self  = (const float*)d_in[0];
    const float* x_neigh = (const float*)d_in[1];
    const float* w_neigh = (const float*)d_in[2];
    const float* w_self  = (const float*)d_in[3];
    const float* bias    = (const float*)d_in[4];
    float* out = (float*)d_out;

    const int rows   = in_sizes[0] / 128;          // 81920
    const int ntiles = rows / RPB;                 // 10240
    const int grid   = 2048;
    const int tpb    = (ntiles + grid - 1) / grid; // 5

    agg_pipe_kernel<<<grid, 256, 0, stream>>>(
        x_self, x_neigh, w_neigh, w_self, bias, out, rows, tpb);
}

// Round 5
// 283.130 us; speedup vs baseline: 1.1212x; 1.1212x over previous
//
#include <hip/hip_runtime.h>

// Aggregator: B=8192, H=10, N=25, F=128, D=256 (half=128). Rows = B*H = 81920.
// out[row][0:128]   = relu(x_self[row]          @ w_self  + bias[0:128])
// out[row][128:256] = relu(mean_n(x_neigh[row]) @ w_neigh + bias[128:256])
//
// R5: true software pipeline. R4 failed because compute-phase GLOBAL weight
// loads drained vmcnt (FIFO) and killed the staged-load overlap. Now weights
// are LDS-resident (loaded once per block); the compute phase touches only
// LDS, so the 25 staged loads for tile t+1 stay in flight through compute of
// tile t. Two kernels so 72 KB dyn-LDS fits 2 blocks/CU.

#define RPB 8

__device__ __forceinline__ void fma4(float4& a, float s, const float4& b) {
    a.x = fmaf(s, b.x, a.x);
    a.y = fmaf(s, b.y, a.y);
    a.z = fmaf(s, b.z, a.z);
    a.w = fmaf(s, b.w, a.w);
}

// ---------------- neighbor half: out[:,128:256] ----------------
__global__ __launch_bounds__(256, 2) void agg_neigh_kernel(
    const float* __restrict__ x_neigh,  // [rows][25][128]
    const float* __restrict__ w_neigh,  // [128][128]
    const float* __restrict__ bias,     // [256]
    float* __restrict__ out,            // [rows][256]
    int ntiles, int tiles_per_block)
{
    extern __shared__ float lds[];
    float* wl = lds;                                    // [128][128] = 64 KB
    float (*ag)[RPB][128] = (float(*)[RPB][128])(lds + 16384);  // dbuf tiles

    const int tid = threadIdx.x;

    // preload w_neigh into LDS (once per block), coalesced float4
    {
        const float4* w4  = (const float4*)w_neigh;
        float4*       wl4 = (float4*)wl;
        #pragma unroll
        for (int i = 0; i < 16; ++i) wl4[i * 256 + tid] = w4[i * 256 + tid];
    }

    const int sr = tid >> 5;   // staging/compute row 0..7
    const int sv = tid & 31;   // staging float4 column
    const int cg = tid & 31;   // compute col-group (4 cols)

    const int tile0 = blockIdx.x * tiles_per_block;
    if (tile0 >= ntiles) return;
    const int tend = min(tile0 + tiles_per_block, ntiles);

    const float4* xn4 = (const float4*)x_neigh;
    const float4 b4 = *(const float4*)&bias[128 + cg * 4];

    float4 st[25];   // staged neighbor rows, in flight across compute

    auto stage = [&](int t) {
        const size_t base = ((size_t)t * RPB + sr) * 800 + sv;  // float4 units
        #pragma unroll
        for (int n = 0; n < 25; ++n) st[n] = xn4[base + n * 32];
    };

    auto reduce_write = [&](int buf) {   // vmcnt wait lands HERE (after compute)
        float4 a = st[0];
        #pragma unroll
        for (int n = 1; n < 25; ++n) {
            a.x += st[n].x; a.y += st[n].y; a.z += st[n].z; a.w += st[n].w;
        }
        const float inv = 1.0f / 25.0f;
        a.x *= inv; a.y *= inv; a.z *= inv; a.w *= inv;
        *(float4*)&ag[buf][sr][sv * 4] = a;
    };

    auto compute_store = [&](int t, int buf) {   // LDS + VALU only
        float4 acc = make_float4(0.f, 0.f, 0.f, 0.f);
        for (int f4 = 0; f4 < 32; ++f4) {
            const float4 xv = *(const float4*)&ag[buf][sr][f4 * 4];  // broadcast
            const float4 w0 = *(const float4*)&wl[(f4 * 4 + 0) * 128 + cg * 4];
            const float4 w1 = *(const float4*)&wl[(f4 * 4 + 1) * 128 + cg * 4];
            const float4 w2 = *(const float4*)&wl[(f4 * 4 + 2) * 128 + cg * 4];
            const float4 w3 = *(const float4*)&wl[(f4 * 4 + 3) * 128 + cg * 4];
            fma4(acc, xv.x, w0);
            fma4(acc, xv.y, w1);
            fma4(acc, xv.z, w2);
            fma4(acc, xv.w, w3);
        }
        float4 o;
        o.x = fmaxf(acc.x + b4.x, 0.f);
        o.y = fmaxf(acc.y + b4.y, 0.f);
        o.z = fmaxf(acc.z + b4.z, 0.f);
        o.w = fmaxf(acc.w + b4.w, 0.f);
        *(float4*)&out[((size_t)t * RPB + sr) * 256 + 128 + cg * 4] = o;
    };

    // prologue
    stage(tile0);
    reduce_write(0);
    __syncthreads();   // also covers the weight preload

    int cur = 0;
    for (int t = tile0; t < tend; ++t) {
        const bool hn = (t + 1 < tend);
        if (hn) stage(t + 1);      // issue loads; no consumer until reduce
        compute_store(t, cur);     // pure LDS/VALU — loads stay in flight
        if (hn) {
            reduce_write(cur ^ 1);
            __syncthreads();
        }
        cur ^= 1;
    }
}

// ---------------- self half: out[:,0:128] ----------------
__global__ __launch_bounds__(256, 2) void agg_self_kernel(
    const float* __restrict__ x_self,   // [rows][128]
    const float* __restrict__ w_self,   // [128][128]
    const float* __restrict__ bias,     // [256]
    float* __restrict__ out,            // [rows][256]
    int ntiles, int tiles_per_block)
{
    extern __shared__ float lds[];
    float* wl = lds;
    float (*xs)[RPB][128] = (float(*)[RPB][128])(lds + 16384);

    const int tid = threadIdx.x;
    {
        const float4* w4  = (const float4*)w_self;
        float4*       wl4 = (float4*)wl;
        #pragma unroll
        for (int i = 0; i < 16; ++i) wl4[i * 256 + tid] = w4[i * 256 + tid];
    }

    const int sr = tid >> 5;
    const int sv = tid & 31;
    const int cg = tid & 31;

    const int tile0 = blockIdx.x * tiles_per_block;
    if (tile0 >= ntiles) return;
    const int tend = min(tile0 + tiles_per_block, ntiles);

    const float4* xs4 = (const float4*)x_self;
    const float4 b4 = *(const float4*)&bias[cg * 4];

    float4 ss;

    auto stage = [&](int t) {
        ss = xs4[((size_t)t * RPB + sr) * 32 + sv];
    };
    auto write_tile = [&](int buf) {
        *(float4*)&xs[buf][sr][sv * 4] = ss;
    };
    auto compute_store = [&](int t, int buf) {
        float4 acc = make_float4(0.f, 0.f, 0.f, 0.f);
        for (int f4 = 0; f4 < 32; ++f4) {
            const float4 xv = *(const float4*)&xs[buf][sr][f4 * 4];
            const float4 w0 = *(const float4*)&wl[(f4 * 4 + 0) * 128 + cg * 4];
            const float4 w1 = *(const float4*)&wl[(f4 * 4 + 1) * 128 + cg * 4];
            const float4 w2 = *(const float4*)&wl[(f4 * 4 + 2) * 128 + cg * 4];
            const float4 w3 = *(const float4*)&wl[(f4 * 4 + 3) * 128 + cg * 4];
            fma4(acc, xv.x, w0);
            fma4(acc, xv.y, w1);
            fma4(acc, xv.z, w2);
            fma4(acc, xv.w, w3);
        }
        float4 o;
        o.x = fmaxf(acc.x + b4.x, 0.f);
        o.y = fmaxf(acc.y + b4.y, 0.f);
        o.z = fmaxf(acc.z + b4.z, 0.f);
        o.w = fmaxf(acc.w + b4.w, 0.f);
        *(float4*)&out[((size_t)t * RPB + sr) * 256 + cg * 4] = o;
    };

    stage(tile0);
    write_tile(0);
    __syncthreads();

    int cur = 0;
    for (int t = tile0; t < tend; ++t) {
        const bool hn = (t + 1 < tend);
        if (hn) stage(t + 1);
        compute_store(t, cur);
        if (hn) {
            write_tile(cur ^ 1);
            __syncthreads();
        }
        cur ^= 1;
    }
}

extern "C" void kernel_launch(void* const* d_in, const int* in_sizes, int n_in,
                              void* d_out, int out_size, void* d_ws, size_t ws_size,
                              hipStream_t stream) {
    const float* x_self  = (const float*)d_in[0];
    const float* x_neigh = (const float*)d_in[1];
    const float* w_neigh = (const float*)d_in[2];
    const float* w_self  = (const float*)d_in[3];
    const float* bias    = (const float*)d_in[4];
    float* out = (float*)d_out;

    const int rows   = in_sizes[0] / 128;   // 81920
    const int ntiles = rows / RPB;          // 10240
    const int grid   = 512;                 // 2 blocks/CU
    const int tpb    = (ntiles + grid - 1) / grid;  // 20

    const size_t shmem = (16384 + 2 * RPB * 128) * sizeof(float);  // 73728 B

    agg_neigh_kernel<<<grid, 256, shmem, stream>>>(
        x_neigh, w_neigh, bias, out, ntiles, tpb);
    agg_self_kernel<<<grid, 256, shmem, stream>>>(
        x_self, w_self, bias, out, ntiles, tpb);
}